// Round 8
// baseline (149.998 us; speedup 1.0000x reference)
//
#include <hip/hip_runtime.h>

// ---------- types / helpers ----------
typedef _Float16 f16x8 __attribute__((ext_vector_type(8)));
typedef _Float16 f16x4 __attribute__((ext_vector_type(4)));
typedef float    f32x4 __attribute__((ext_vector_type(4)));

#define MFMA_F16(a, b, c) __builtin_amdgcn_mfma_f32_16x16x32_f16((a), (b), (c), 0, 0, 0)

typedef __attribute__((address_space(1))) void gas_void;
typedef __attribute__((address_space(3))) void las_void;
// 16B/lane direct global->LDS (dest = wave-uniform base + lane*16)
#define GLOAD_LDS16(g, l) \
  __builtin_amdgcn_global_load_lds((gas_void*)(g), (las_void*)(l), 16, 0, 0)

#define NEG_INF (-__builtin_inff())

constexpr int T_SEQ  = 2048;
constexpr int HID    = 1024;
constexpr int NHEADS = 16;
constexpr int DH     = 64;
constexpr int NSEG   = 8;

// ---------- kernel 1: fp32 -> fp16 convert (x + 4 weights) ----------
// Convert-fusion axis CLOSED (R15: reg-staged convert in GEMM -> 153us).
__global__ __launch_bounds__(256) void convert_all(
    const float* __restrict__ x,
    const float* __restrict__ Wq, const float* __restrict__ Wk,
    const float* __restrict__ Wv, const float* __restrict__ Wo,
    _Float16* __restrict__ xh,
    _Float16* __restrict__ Wqh, _Float16* __restrict__ Wkh,
    _Float16* __restrict__ Wvh, _Float16* __restrict__ Woh) {
  int i = blockIdx.x * 256 + threadIdx.x;  // float4 index
  const float* src;
  _Float16* dst;
  int local;
  if (i < 524288) {
    src = x; dst = xh; local = i;
  } else {
    int j = i - 524288;
    int w = j >> 18;          // 262144 = 2^18 float4 per weight
    local = j & 262143;
    src = (w == 0) ? Wq : (w == 1) ? Wk : (w == 2) ? Wv : Wo;
    dst = (w == 0) ? Wqh : (w == 1) ? Wkh : (w == 2) ? Wvh : Woh;
  }
  float4 f = *(const float4*)(src + (size_t)local * 4);
  f16x4 h;
  h[0] = (_Float16)f.x; h[1] = (_Float16)f.y;
  h[2] = (_Float16)f.z; h[3] = (_Float16)f.w;
  *(f16x4*)(dst + (size_t)local * 4) = h;
}

// ---------- NT GEMM: C[m][n] = sum_k A[m][k]*B[n][k] + bias[n] ----------
// R14 core (known-good): 256 threads = 4 waves (2x2 wave grid), tile BM x BN,
// BK=64, XOR-swizzled LDS via global_load_lds, single-buffered 2-barrier
// K-loop. Grid balance: qkv 768 blocks = exactly 3/CU, out 512 = exactly
// 2/CU -- cross-block co-residency hides the barrier drain (m114).
// CLOSED axes: source-level dbuf pipelining (R10/R12), fp32 reg-staging (R15).
// Output layouts: 0 = f16 head-major [NH][T][DH]; 1 = f32 [T][N];
//                 3 = f16 transposed [N][T] (for V^T), f16x4 over rows.
template <int LAYOUT, int BM, int BN>
__device__ __forceinline__ void gemm_t(const _Float16* __restrict__ A,
                                       const _Float16* __restrict__ B,
                                       const float* __restrict__ bias,
                                       _Float16* __restrict__ outh,
                                       float* __restrict__ outf) {
  constexpr int K = HID, N = HID;
  constexpr int MI = BM / 32;              // m-subtiles per wave (wave = BM/2 rows)
  constexpr int NI = BN / 32;              // n-subtiles per wave (wave = BN/2 cols)
  constexpr int LA = (BM * 64) / (256 * 8);  // A-staging loads per lane
  constexpr int LB = (BN * 64) / (256 * 8);  // B-staging loads per lane
  __shared__ _Float16 As[BM * 64];
  __shared__ _Float16 Bs[BN * 64];
  const int tid  = threadIdx.x;
  const int wave = tid >> 6, lane = tid & 63;
  const int lr = lane & 15, lq = lane >> 4;
  const int wm = (wave >> 1) * (BM / 2);   // 2 wave-rows
  const int wn = (wave & 1) * (BN / 2);    // 2 wave-cols
  const int bm = blockIdx.y * BM, bn = blockIdx.x * BN;

  const _Float16* gA[LA];
  const _Float16* gB[LB];
  _Float16* lA[LA];
  _Float16* lB[LB];
#pragma unroll
  for (int i = 0; i < LA; ++i) {
    const int s = i * 256 + tid;
    const int row = s >> 3, pch = s & 7;
    const int lch = pch ^ (row & 7);
    gA[i] = A + (size_t)(bm + row) * K + lch * 8;
    lA[i] = &As[(i * 256 + wave * 64) * 8];  // wave-uniform base
  }
#pragma unroll
  for (int i = 0; i < LB; ++i) {
    const int s = i * 256 + tid;
    const int row = s >> 3, pch = s & 7;
    const int lch = pch ^ (row & 7);
    gB[i] = B + (size_t)(bn + row) * K + lch * 8;
    lB[i] = &Bs[(i * 256 + wave * 64) * 8];
  }

  f32x4 acc[MI][NI] = {};

  for (int kk = 0; kk < K; kk += 64) {
#pragma unroll
    for (int i = 0; i < LA; ++i) GLOAD_LDS16(gA[i] + kk, lA[i]);
#pragma unroll
    for (int i = 0; i < LB; ++i) GLOAD_LDS16(gB[i] + kk, lB[i]);
    __syncthreads();
#pragma unroll
    for (int ks = 0; ks < 2; ++ks) {
      f16x8 af[MI], bf[NI];
#pragma unroll
      for (int mi = 0; mi < MI; ++mi) {
        const int row = wm + mi * 16 + lr;
        af[mi] = *(const f16x8*)&As[row * 64 + (((ks * 4 + lq) ^ (row & 7)) * 8)];
      }
#pragma unroll
      for (int ni = 0; ni < NI; ++ni) {
        const int row = wn + ni * 16 + lr;
        bf[ni] = *(const f16x8*)&Bs[row * 64 + (((ks * 4 + lq) ^ (row & 7)) * 8)];
      }
#pragma unroll
      for (int mi = 0; mi < MI; ++mi)
#pragma unroll
        for (int ni = 0; ni < NI; ++ni)
          acc[mi][ni] = MFMA_F16(af[mi], bf[ni], acc[mi][ni]);
    }
    __syncthreads();
  }

  // epilogue: C/D layout col = lane&15, row = (lane>>4)*4 + reg
#pragma unroll
  for (int ni = 0; ni < NI; ++ni) {
    const int col = bn + wn + ni * 16 + lr;
    const float bv = bias[col];
#pragma unroll
    for (int mi = 0; mi < MI; ++mi) {
      const f32x4 v = acc[mi][ni];
      const int row0 = bm + wm + mi * 16 + lq * 4;
      if (LAYOUT == 3) {
        f16x4 o;
#pragma unroll
        for (int r = 0; r < 4; ++r) o[r] = (_Float16)(v[r] + bv);
        *(f16x4*)&outh[(size_t)col * T_SEQ + row0] = o;
      } else {
#pragma unroll
        for (int r = 0; r < 4; ++r) {
          const int row = row0 + r;
          const float val = v[r] + bv;
          if (LAYOUT == 0)
            outh[((size_t)(col >> 6) * T_SEQ + row) * DH + (col & 63)] = (_Float16)val;
          else
            outf[(size_t)row * N + col] = val;
        }
      }
    }
  }
}

__global__ __launch_bounds__(256) void gemm_qkv(
    const _Float16* __restrict__ xh,
    const _Float16* __restrict__ Wqh, const _Float16* __restrict__ Wkh,
    const _Float16* __restrict__ Wvh,
    const float* __restrict__ bq, const float* __restrict__ bk,
    const float* __restrict__ bv,
    _Float16* __restrict__ qp, _Float16* __restrict__ kp,
    _Float16* __restrict__ vT) {
  const int z = blockIdx.z;
  if (z == 0) {
    gemm_t<0, 64, 128>(xh, Wqh, bq, qp, nullptr);   // Q head-major [NH][T][DH]
  } else if (z == 1) {
    gemm_t<0, 64, 128>(xh, Wkh, bk, kp, nullptr);   // K head-major [NH][T][DH]
  } else {
    gemm_t<3, 64, 128>(xh, Wvh, bv, vT, nullptr);   // V transposed [NH][DH][T]
  }
}

__global__ __launch_bounds__(256) void gemm_out(
    const _Float16* __restrict__ ctxh, const _Float16* __restrict__ Woh,
    const float* __restrict__ bo, float* __restrict__ out) {
  gemm_t<1, 64, 64>(ctxh, Woh, bo, nullptr, out);   // 64x64 tiles -> 512 blocks
}

// ---------- kernel 3: flash attention, DE-STAGED (K/V direct from L2) ------
// R17: LDS K/V staging + per-step barriers REMOVED. KV working set is
// XCD-local-L2-resident (~1MB/XCD, R9/R16 swizzle), so staging was pure
// overhead (guide common-mistake #7 / m169). MFMA B-fragments are read
// directly from global: per-lane 16B addresses = the unswizzled fragment
// layout. With no barriers in the K-loop, per-wave trip counts are legal
// (R13's lesson applied correctly): each wave iterates ONLY its own
// segment-half [st,en), not the block's 64-query union -- straddle blocks
// stop paying both segments in every wave. Split-K halves partition keys
// exactly (64-aligned mid, masks clamp to [max(sstart,st), min(send,en))),
// so results are bit-identical. LDS 50KB -> 34.5KB (Pl + dedicated merge).
__device__ __forceinline__ float redsum16(float v) {
  v += __shfl_xor(v, 1);
  v += __shfl_xor(v, 2);
  v += __shfl_xor(v, 4);
  v += __shfl_xor(v, 8);
  return v;
}

// grid 512 x 1; q,k: [NH][T][DH] f16; vT: [NH][DH][T] f16; ctx: [T][HID] f16.
__global__ __launch_bounds__(512, 4) void attn_kernel(
    const _Float16* __restrict__ qp, const _Float16* __restrict__ kp,
    const _Float16* __restrict__ vT, const int* __restrict__ cu,
    _Float16* __restrict__ ctx) {
  constexpr float SCL2E = 0.125f * 1.44269504f;  // scale * log2(e)
  constexpr int PSTR = 72;                        // multiple of 8 (16B-aligned rows)
  __shared__ _Float16 Pl[8][16 * PSTR];  // 18 KB per-wave P tiles
  __shared__ float mO[4][16][64];        // 16 KB split-K merge
  __shared__ float mL[4][16];
  // R16 decode: xcd = bx&7; same-XCD-adjacent blocks carry q-tiles 1024
  // tokens apart (work decorrelation), h%8 == bx%8 (XCD KV locality).
  const int bx   = blockIdx.x;
  const int xcd  = bx & 7;
  const int idx  = bx >> 3;            // 0..63 within XCD
  const int hsel = idx & 1;
  const int h    = xcd + 8 * hsel;
  const int q0   = ((((idx >> 1) + hsel * 16) & 31)) * 64;
  const int tid = threadIdx.x, wave = tid >> 6, lane = tid & 63;
  const int lr = lane & 15, lq = lane >> 4;
  const int qsub = wave & 3, khalf = wave >> 2;
  const int qw = q0 + qsub * 16;

  int cs[NSEG + 1];
#pragma unroll
  for (int i = 0; i <= NSEG; ++i) cs[i] = cu[i];

  // per-C-reg rows: row = qw + lq*4 + r
  int sstart[4], send[4];
#pragma unroll
  for (int r = 0; r < 4; ++r) {
    const int row = qw + lq * 4 + r;
    sstart[r] = 0; send[r] = T_SEQ;
#pragma unroll
    for (int s = 0; s < NSEG; ++s)
      if (row >= cs[s] && row < cs[s + 1]) { sstart[r] = cs[s]; send[r] = cs[s + 1]; }
  }
  // wave-level segment bounds: first row's segment and last row's segment
  int wlo = 0, whi = T_SEQ, wlo2 = 0, whi2 = T_SEQ;
#pragma unroll
  for (int s = 0; s < NSEG; ++s) {
    if (qw >= cs[s] && qw < cs[s + 1]) { wlo = cs[s]; whi = cs[s + 1]; }
    if (qw + 15 >= cs[s] && qw + 15 < cs[s + 1]) { wlo2 = cs[s]; whi2 = cs[s + 1]; }
  }
  const bool wsame = (wlo == wlo2);
  // wave's key range = union of its rows' segments = [a, b)
  const int a = wlo, b = whi2;
  const int t0    = a & ~63;                 // first tile
  const int ntile = (b - t0 + 63) >> 6;      // total tiles for this wave
  const int nt0   = (ntile + 1) >> 1;        // tiles for khalf 0
  const int tiles = khalf ? (ntile - nt0) : nt0;
  const int tstart = khalf ? (t0 + nt0 * 64) : t0;
  const int mid   = t0 + nt0 * 64;           // 64-aligned key split
  const int st    = khalf ? mid : a;
  const int en    = khalf ? b : (mid < b ? mid : b);
  int vlo[4], vhi[4];
#pragma unroll
  for (int r = 0; r < 4; ++r) {
    vlo[r] = sstart[r] > st ? sstart[r] : st;
    vhi[r] = send[r] < en ? send[r] : en;
  }

  // Q fragments (A-operand: m = lane&15 = query, k = lq*8+j), pre-scaled by
  // scale*log2e so the post-MFMA score is already in log2 units.
  const _Float16* qbase = qp + ((size_t)h * T_SEQ + qw + lr) * DH;
  f16x8 qf0 = *(const f16x8*)(qbase + lq * 8);
  f16x8 qf1 = *(const f16x8*)(qbase + 32 + lq * 8);
#pragma unroll
  for (int i = 0; i < 8; ++i) {
    qf0[i] = qf0[i] * (_Float16)SCL2E;
    qf1[i] = qf1[i] * (_Float16)SCL2E;
  }

  const _Float16* kb = kp + (size_t)h * T_SEQ * DH;
  const _Float16* vb = vT + (size_t)h * DH * T_SEQ;

  float lst[4] = {0.f, 0.f, 0.f, 0.f};
  f32x4 oacc[4];
#pragma unroll
  for (int c = 0; c < 4; ++c) oacc[c] = f32x4{0.f, 0.f, 0.f, 0.f};

  _Float16* pw = &Pl[wave][0];

  for (int s = 0; s < tiles; ++s) {
    const int kt = tstart + s * 64;
    // QK: B-frags direct from global (L2-hot); key = kt + n*16 + lr,
    // dh chunk = lq*8 (kf0) / 32+lq*8 (kf1).
    f32x4 sc[4];
#pragma unroll
    for (int n = 0; n < 4; ++n) {
      const _Float16* kr = kb + (size_t)(kt + n * 16 + lr) * DH + lq * 8;
      const f16x8 kf0 = *(const f16x8*)kr;
      const f16x8 kf1 = *(const f16x8*)(kr + 32);
      sc[n] = f32x4{0.f, 0.f, 0.f, 0.f};
      sc[n] = MFMA_F16(qf0, kf0, sc[n]);
      sc[n] = MFMA_F16(qf1, kf1, sc[n]);
    }
    // fixed-base softmax, P to per-wave LDS. Fast path: tile fully inside
    // this wave's valid key window (wsame => all rows share [st,en)).
    const bool fastTile = wsame && (kt >= st) && (kt + 64 <= en);
    if (fastTile) {
#pragma unroll
      for (int r = 0; r < 4; ++r) {
        float p[4];
#pragma unroll
        for (int n = 0; n < 4; ++n) p[n] = exp2f(sc[n][r]);
        lst[r] += (p[0] + p[1]) + (p[2] + p[3]);
        _Float16* pr = &pw[(lq * 4 + r) * PSTR + lr];
        pr[0]  = (_Float16)p[0];
        pr[16] = (_Float16)p[1];
        pr[32] = (_Float16)p[2];
        pr[48] = (_Float16)p[3];
      }
    } else {
#pragma unroll
      for (int r = 0; r < 4; ++r) {
        float p[4];
#pragma unroll
        for (int n = 0; n < 4; ++n) {
          const int col = kt + n * 16 + lr;
          const float vv =
              (col >= vlo[r] && col < vhi[r]) ? sc[n][r] : NEG_INF;
          p[n] = exp2f(vv);  // masked -> 0
        }
        lst[r] += (p[0] + p[1]) + (p[2] + p[3]);
        _Float16* pr = &pw[(lq * 4 + r) * PSTR + lr];
        pr[0]  = (_Float16)p[0];
        pr[16] = (_Float16)p[1];
        pr[32] = (_Float16)p[2];
        pr[48] = (_Float16)p[3];
      }
    }
    // PV: A-frag = P (same-wave LDS RAW), B-frags direct from global:
    // dh = c*16 + lr, key chunk = kt + lq*8 (vf0) / kt+32+lq*8 (vf1).
    const f16x8 pf0 = *(const f16x8*)&pw[lr * PSTR + lq * 8];
    const f16x8 pf1 = *(const f16x8*)&pw[lr * PSTR + 32 + lq * 8];
#pragma unroll
    for (int c = 0; c < 4; ++c) {
      const _Float16* vr = vb + (size_t)(c * 16 + lr) * T_SEQ + kt + lq * 8;
      const f16x8 vf0 = *(const f16x8*)vr;
      const f16x8 vf1 = *(const f16x8*)(vr + 32);
      oacc[c] = MFMA_F16(pf0, vf0, oacc[c]);
      oacc[c] = MFMA_F16(pf1, vf1, oacc[c]);
    }
  }

  // reduce l across the 16 key-lanes
#pragma unroll
  for (int r = 0; r < 4; ++r) lst[r] = redsum16(lst[r]);

  // split-K merge: waves 4-7 deposit; waves 0-3 combine + store
  if (khalf) {
#pragma unroll
    for (int c = 0; c < 4; ++c)
#pragma unroll
      for (int r = 0; r < 4; ++r)
        mO[qsub][lq * 4 + r][c * 16 + lr] = oacc[c][r];
    if (lr == 0) {
#pragma unroll
      for (int r = 0; r < 4; ++r) mL[qsub][lq * 4 + r] = lst[r];
    }
  }
  __syncthreads();
  if (!khalf) {
#pragma unroll
    for (int r = 0; r < 4; ++r) lst[r] += mL[qsub][lq * 4 + r];
#pragma unroll
    for (int c = 0; c < 4; ++c)
#pragma unroll
      for (int r = 0; r < 4; ++r) {
        const int row = qw + lq * 4 + r;
        const float val =
            (oacc[c][r] + mO[qsub][lq * 4 + r][c * 16 + lr]) / lst[r];
        ctx[(size_t)row * HID + h * DH + c * 16 + lr] = (_Float16)val;
      }
  }
}

// ---------- launch ----------
extern "C" void kernel_launch(void* const* d_in, const int* in_sizes, int n_in,
                              void* d_out, int out_size, void* d_ws, size_t ws_size,
                              hipStream_t stream) {
  const float* x  = (const float*)d_in[0];
  const int* cu   = (const int*)d_in[1];
  const float* Wq = (const float*)d_in[2]; const float* bq = (const float*)d_in[3];
  const float* Wk = (const float*)d_in[4]; const float* bk = (const float*)d_in[5];
  const float* Wv = (const float*)d_in[6]; const float* bv = (const float*)d_in[7];
  const float* Wo = (const float*)d_in[8]; const float* bo = (const float*)d_in[9];
  float* out = (float*)d_out;

  char* ws = (char*)d_ws;
  _Float16* xh   = (_Float16*)(ws + (size_t)0);              // [T][HID] f16
  _Float16* Wqh  = (_Float16*)(ws + ((size_t)4 << 20));
  _Float16* Wkh  = (_Float16*)(ws + ((size_t)6 << 20));
  _Float16* Wvh  = (_Float16*)(ws + ((size_t)8 << 20));
  _Float16* Woh  = (_Float16*)(ws + ((size_t)10 << 20));
  _Float16* qp   = (_Float16*)(ws + ((size_t)12 << 20));  // [NH][T][DH]
  _Float16* kp   = (_Float16*)(ws + ((size_t)16 << 20));  // [NH][T][DH]
  _Float16* vT   = (_Float16*)(ws + ((size_t)20 << 20));  // [NH][DH][T]
  _Float16* ctxh = (_Float16*)(ws + ((size_t)24 << 20));  // [T][HID]

  convert_all<<<6144, 256, 0, stream>>>(x, Wq, Wk, Wv, Wo, xh, Wqh, Wkh, Wvh, Woh);
  gemm_qkv<<<dim3(8, 32, 3), 256, 0, stream>>>(xh, Wqh, Wkh, Wvh, bq, bk, bv, qp, kp, vT);
  attn_kernel<<<512, 512, 0, stream>>>(qp, kp, vT, cu, ctxh);
  gemm_out<<<dim3(16, 32), 256, 0, stream>>>(ctxh, Woh, bo, out);
}